// Round 1
// baseline (1354.608 us; speedup 1.0000x reference)
//
#include <hip/hip_runtime.h>
#include <hip/hip_bf16.h>
#include <stdint.h>

#define B 8
#define N 4096
#define C 1024
#define H 16
#define D 64
// SCALE = D^-0.5 = 0.125

static __device__ __forceinline__ float bf_lo(uint32_t u) {
    union { uint32_t i; float f; } c; c.i = u << 16; return c.f;
}
static __device__ __forceinline__ float bf_hi(uint32_t u) {
    union { uint32_t i; float f; } c; c.i = u & 0xffff0000u; return c.f;
}

// Kernel A: one wave per W row r (0..2C); computes k[b,*,r] (r<C) or v (r>=C)
// for ALL 8 batches -> W read exactly once. emb (32 KB) stays L2-hot.
__global__ __launch_bounds__(256, 2)
void kv_kernel(const float* __restrict__ emb,
               const float* __restrict__ Wk,
               const float* __restrict__ Wv,
               float* __restrict__ kbuf,
               float* __restrict__ vbuf) {
    int wave = (blockIdx.x * blockDim.x + threadIdx.x) >> 6;  // 0..2047
    int lane = threadIdx.x & 63;
    int r = wave;
    const float* Wrow = (r < C) ? (Wk + (size_t)r * C) : (Wv + (size_t)(r - C) * C);
    float4 w4[4];
#pragma unroll
    for (int j = 0; j < 4; ++j) w4[j] = *(const float4*)(Wrow + (lane + 64 * j) * 4);
    float acc[B];
#pragma unroll
    for (int b = 0; b < B; ++b) {
        const float* e = emb + (size_t)b * C;
        float a = 0.f;
#pragma unroll
        for (int j = 0; j < 4; ++j) {
            float4 e4 = *(const float4*)(e + (lane + 64 * j) * 4);
            a += w4[j].x * e4.x + w4[j].y * e4.y + w4[j].z * e4.z + w4[j].w * e4.w;
        }
        acc[b] = a;
    }
#pragma unroll
    for (int off = 32; off; off >>= 1)
#pragma unroll
        for (int b = 0; b < B; ++b) acc[b] += __shfl_xor(acc[b], off, 64);
    if (lane == 0) {
        float* dst = (r < C) ? (kbuf + r) : (vbuf + (r - C));
#pragma unroll
        for (int b = 0; b < B; ++b) dst[b * C] = acc[b];
    }
}

// Kernel B: fold weights. block = (b,h,which).
//   which==0: w[b,h,c]  = sum_d Wq[(hD+d)*C + c] * k[b,h,d]   (bf16 out)
//   which==1: U[b,h,c'] = sum_d Wp[c'*C + hD + d] * v[b,h,d]  (bf16 out)
__global__ __launch_bounds__(256, 2)
void wu_kernel(const float* __restrict__ Wq,
               const float* __restrict__ Wp,
               const float* __restrict__ kbuf,
               const float* __restrict__ vbuf,
               __hip_bfloat16* __restrict__ wbuf,
               __hip_bfloat16* __restrict__ ubuf) {
    int id = blockIdx.x;
    int which = id & 1; id >>= 1;
    int h = id % H;
    int b = id / H;
    int t = threadIdx.x;
    if (which == 0) {
        const float* kk = kbuf + (size_t)(b * H + h) * D;
        int c = t * 4;
        float4 acc = {0.f, 0.f, 0.f, 0.f};
#pragma unroll 8
        for (int d = 0; d < D; ++d) {
            float kvs = kk[d];
            float4 w4 = *(const float4*)(Wq + (size_t)(h * D + d) * C + c);
            acc.x += kvs * w4.x; acc.y += kvs * w4.y;
            acc.z += kvs * w4.z; acc.w += kvs * w4.w;
        }
        __hip_bfloat16* o = wbuf + (size_t)(b * H + h) * C + c;
        o[0] = __float2bfloat16(acc.x); o[1] = __float2bfloat16(acc.y);
        o[2] = __float2bfloat16(acc.z); o[3] = __float2bfloat16(acc.w);
    } else {
        // 4 lanes per output row c'; lane-in-group q covers d = q*16 + 0..15.
        const int q = t & 3;
        const float* vv = vbuf + (size_t)(b * H + h) * D + q * 16;
        float4 v4[4];
#pragma unroll
        for (int m = 0; m < 4; ++m) v4[m] = *(const float4*)(vv + m * 4);
#pragma unroll
        for (int p = 0; p < 16; ++p) {
            int cp = p * 64 + (t >> 2);
            const float* wp = Wp + (size_t)cp * C + h * D + q * 16;
            float acc = 0.f;
#pragma unroll
            for (int m = 0; m < 4; ++m) {
                float4 w4 = *(const float4*)(wp + m * 4);
                acc += w4.x * v4[m].x + w4.y * v4[m].y
                     + w4.z * v4[m].z + w4.w * v4[m].w;
            }
            acc += __shfl_xor(acc, 1, 64);
            acc += __shfl_xor(acc, 2, 64);
            if (q == 0) ubuf[(size_t)(b * H + h) * C + cp] = __float2bfloat16(acc);
        }
    }
}

// Kernel C: fused main pass, restructured for latency tolerance.
// One wave per row, 16 rows/wave. grid = (64, B), block = 256 (4 waves).
// LDS = 64KB -> 2 blocks/CU (8 waves/CU).
// Changes vs previous version:
//  - Packed per-head partials s[16] per lane + ONE 6-step x 16-value
//    butterfly (16-way ILP on every shuffle step; no per-head serial
//    chains, no divergent lane==h select, no readlane broadcast array).
//  - Uniform sigmoid on all lanes (result identical across lanes after
//    full butterfly) -> epilogue reads s[h] directly from VGPRs.
//  - Software-pipelined rows: double-buffered f registers; next row's
//    4x dwordx4 loads issue before the butterfly so HBM latency hides
//    under ~1.5K cycles of compute.
//  - Small live state (~80 VGPRs); no amdgpu_waves_per_eu pin.
// Numerics are bit-identical to the previous kernel (same partials,
// same butterfly order, same epilogue order).
__global__ __launch_bounds__(256, 2)
void main_kernel(const float* __restrict__ fea,
                 const __hip_bfloat16* __restrict__ wbuf,
                 const __hip_bfloat16* __restrict__ ubuf,
                 const float* __restrict__ bp,
                 float* __restrict__ out) {
    __shared__ uint32_t w_s[H * C / 2];  // bf16x2 packed, 32 KB
    __shared__ uint32_t u_s[H * C / 2];  // 32 KB
    const int b = blockIdx.y;
    const int tile = blockIdx.x;
    const int tid = threadIdx.x;

    {
        const uint4* wsrc = (const uint4*)(wbuf + (size_t)b * H * C);
        const uint4* usrc = (const uint4*)(ubuf + (size_t)b * H * C);
        uint4* wdst = (uint4*)w_s;
        uint4* udst = (uint4*)u_s;
#pragma unroll
        for (int i = 0; i < H * C / 8 / 256; ++i) {
            wdst[tid + i * 256] = wsrc[tid + i * 256];
            udst[tid + i * 256] = usrc[tid + i * 256];
        }
    }
    __syncthreads();

    const int lane = tid & 63;
    const int wv = tid >> 6;          // 0..3
    const int row0 = tile * 64 + wv * 16;

    float4 bp4[4];
#pragma unroll
    for (int j = 0; j < 4; ++j) bp4[j] = *(const float4*)(bp + 4 * lane + 256 * j);

    const float* frow = fea + ((size_t)b * N + row0) * C + 4 * lane;
    float* orow = out + ((size_t)b * N + row0) * C + 4 * lane;

    float4 fa[4];
#pragma unroll
    for (int j = 0; j < 4; ++j) fa[j] = *(const float4*)(frow + 256 * j);

#pragma unroll 2
    for (int i = 0; i < 16; ++i) {
        // Prefetch next row early: consumed only at the bottom of this
        // iteration, so the vmcnt wait lands after the butterfly+epilogue.
        float4 fb[4];
        if (i < 15) {
            const float* fn = frow + (size_t)(i + 1) * C;
#pragma unroll
            for (int j = 0; j < 4; ++j) fb[j] = *(const float4*)(fn + 256 * j);
        }

        // Per-lane partial dot for ALL 16 heads (each lane covers its
        // 16 fea columns; 256 FMA/lane, 64 ds_read_b64).
        float s[H];
#pragma unroll
        for (int h = 0; h < H; ++h) {
            const uint32_t* wrow = w_s + h * (C / 2) + 2 * lane;
            float acc = 0.f;
#pragma unroll
            for (int j = 0; j < 4; ++j) {
                uint2 p = *(const uint2*)(wrow + 128 * j);
                acc += fa[j].x * bf_lo(p.x) + fa[j].y * bf_hi(p.x)
                     + fa[j].z * bf_lo(p.y) + fa[j].w * bf_hi(p.y);
            }
            s[h] = acc;
        }

        // One packed butterfly: 6 steps x 16 independent values.
#pragma unroll
        for (int off = 32; off; off >>= 1) {
#pragma unroll
            for (int h = 0; h < H; ++h) s[h] += __shfl_xor(s[h], off, 64);
        }

        // Uniform sigmoid (identical on all lanes; no broadcast needed).
#pragma unroll
        for (int h = 0; h < H; ++h) s[h] = 1.f / (1.f + __expf(-0.125f * s[h]));

        // Epilogue: out = fea + bp + sum_h a_h * U_h
        float* op = orow + (size_t)i * C;
#pragma unroll
        for (int j = 0; j < 4; ++j) {
            float4 acc = fa[j];
            acc.x += bp4[j].x; acc.y += bp4[j].y;
            acc.z += bp4[j].z; acc.w += bp4[j].w;
            const uint32_t* urow = u_s + 2 * lane + 128 * j;
#pragma unroll
            for (int h = 0; h < H; ++h) {
                uint2 p = *(const uint2*)(urow + h * (C / 2));
                acc.x += s[h] * bf_lo(p.x); acc.y += s[h] * bf_hi(p.x);
                acc.z += s[h] * bf_lo(p.y); acc.w += s[h] * bf_hi(p.y);
            }
            *(float4*)(op + 256 * j) = acc;
        }

        if (i < 15) {
#pragma unroll
            for (int j = 0; j < 4; ++j) fa[j] = fb[j];
        }
    }
}

extern "C" void kernel_launch(void* const* d_in, const int* in_sizes, int n_in,
                              void* d_out, int out_size, void* d_ws, size_t ws_size,
                              hipStream_t stream) {
    const float* fea = (const float*)d_in[0];
    const float* emb = (const float*)d_in[1];
    const float* Wq  = (const float*)d_in[2];
    const float* Wk  = (const float*)d_in[3];
    const float* Wv  = (const float*)d_in[4];
    const float* Wp  = (const float*)d_in[5];
    const float* bp  = (const float*)d_in[6];
    float* out = (float*)d_out;

    char* ws = (char*)d_ws;
    float* kbuf = (float*)ws;                                  // B*C f32 = 32KB
    float* vbuf = (float*)(ws + 32 * 1024);                    // 32KB
    __hip_bfloat16* wbuf = (__hip_bfloat16*)(ws + 64 * 1024);  // B*H*C bf16 = 256KB
    __hip_bfloat16* ubuf = (__hip_bfloat16*)(ws + 320 * 1024); // 256KB

    hipLaunchKernelGGL(kv_kernel, dim3(2 * C / 4), dim3(256), 0, stream,
                       emb, Wk, Wv, kbuf, vbuf);
    hipLaunchKernelGGL(wu_kernel, dim3(B * H * 2), dim3(256), 0, stream,
                       Wq, Wp, kbuf, vbuf, wbuf, ubuf);
    hipLaunchKernelGGL(main_kernel, dim3(N / 64, B), dim3(256), 0, stream,
                       fea, wbuf, ubuf, bp, out);
}